// Round 12
// baseline (971.672 us; speedup 1.0000x reference)
//
#include <hip/hip_runtime.h>
#include <hip/hip_bf16.h>

typedef __attribute__((ext_vector_type(4))) float f32x4;
typedef __attribute__((ext_vector_type(8))) short short8;
typedef __attribute__((ext_vector_type(4))) int i32x4;
typedef __attribute__((ext_vector_type(2))) unsigned int u32x2;
typedef __attribute__((ext_vector_type(4))) unsigned short u16x4;

static __device__ __forceinline__ unsigned short f2bf(float f) {
  unsigned u = __builtin_bit_cast(unsigned, f);
  u = u + 0x7FFFu + ((u >> 16) & 1u);   // RNE
  return (unsigned short)(u >> 16);
}
static __device__ __forceinline__ float bf2f(unsigned short b) {
  unsigned u = ((unsigned)b) << 16;
  return __builtin_bit_cast(float, u);
}
static __device__ __forceinline__ float sigmoidf_fast(float x) {
  return __builtin_amdgcn_rcpf(1.f + __expf(-x));
}
// packed bf16 pair: low16 = bf16(a), high16 = bf16(b)
static __device__ __forceinline__ unsigned cvt_pk_bf16(float a, float b) {
  unsigned d;
  asm volatile("v_cvt_pk_bf16_f32 %0, %1, %2" : "=v"(d) : "v"(a), "v"(b));
  return d;
}
// Row-wise (16-lane DPP row) inclusive sum; total lands in lane (lane&15)==15.
static __device__ __forceinline__ float row_sum16(float v) {
  int x;
  x = __builtin_amdgcn_update_dpp(0, __builtin_bit_cast(int, v), 0x111, 0xF, 0xF, true);
  v += __builtin_bit_cast(float, x);   // row_shr:1
  x = __builtin_amdgcn_update_dpp(0, __builtin_bit_cast(int, v), 0x112, 0xF, 0xF, true);
  v += __builtin_bit_cast(float, x);   // row_shr:2
  x = __builtin_amdgcn_update_dpp(0, __builtin_bit_cast(int, v), 0x114, 0xF, 0xF, true);
  v += __builtin_bit_cast(float, x);   // row_shr:4
  x = __builtin_amdgcn_update_dpp(0, __builtin_bit_cast(int, v), 0x118, 0xF, 0xF, true);
  v += __builtin_bit_cast(float, x);   // row_shr:8
  return v;
}

// ---------------- cast f32 -> hi/lo bf16 pair (RNE hi) ----------------
__global__ void cast_split_kernel(const float* __restrict__ in,
                                  unsigned short* __restrict__ oh,
                                  unsigned short* __restrict__ ol, int n4) {
  int i = blockIdx.x * blockDim.x + threadIdx.x;
  if (i >= n4) return;
  f32x4 v = ((const f32x4*)in)[i];
  u16x4 h, l;
#pragma unroll
  for (int j = 0; j < 4; ++j) {
    unsigned short hb = f2bf(v[j]);
    h[j] = hb;
    l[j] = f2bf(v[j] - bf2f(hb));
  }
  ((u16x4*)oh)[i] = h;
  ((u16x4*)ol)[i] = l;
}

// ---------------- transpose + cast: (R,C) f32 -> (C,R) bf16 ----------------
__global__ void tcast_kernel(const float* __restrict__ in,
                             unsigned short* __restrict__ out, int R, int C) {
  int i = blockIdx.x * blockDim.x + threadIdx.x;
  if (i >= R * C) return;
  int r = i / C, c = i % C;
  out[(size_t)c * R + r] = f2bf(in[i]);
}

// ---------------- transpose + split cast: (R,C) f32 -> (C,R) hi/lo bf16 ----------------
__global__ void tcast_split_kernel(const float* __restrict__ in,
                                   unsigned short* __restrict__ oh,
                                   unsigned short* __restrict__ ol, int R, int C) {
  int i = blockIdx.x * blockDim.x + threadIdx.x;
  if (i >= R * C) return;
  int r = i / C, c = i % C;
  float v = in[i];
  unsigned short hb = f2bf(v);
  oh[(size_t)c * R + r] = hb;
  ol[(size_t)c * R + r] = f2bf(v - bf2f(hb));
}

// ---------------- f gate: one wave per token row (pure f32) ----------------
__global__ __launch_bounds__(256) void fgate_kernel(const float* __restrict__ x,
                                                    const float* __restrict__ Wf,
                                                    const float* __restrict__ bfv,
                                                    float* __restrict__ fbuf) {
  int wid = (blockIdx.x * blockDim.x + threadIdx.x) >> 6;  // token row 0..4095
  int lane = threadIdx.x & 63;
  const float* xr = x + (size_t)wid * 1024;
  float acc[8] = {0.f, 0.f, 0.f, 0.f, 0.f, 0.f, 0.f, 0.f};
#pragma unroll 4
  for (int it = 0; it < 16; ++it) {
    int d = it * 64 + lane;
    float xv = xr[d];
    f32x4 w0 = *(const f32x4*)(Wf + (size_t)d * 8);
    f32x4 w1 = *(const f32x4*)(Wf + (size_t)d * 8 + 4);
    acc[0] += xv * w0[0]; acc[1] += xv * w0[1];
    acc[2] += xv * w0[2]; acc[3] += xv * w0[3];
    acc[4] += xv * w1[0]; acc[5] += xv * w1[1];
    acc[6] += xv * w1[2]; acc[7] += xv * w1[3];
  }
#pragma unroll
  for (int n = 0; n < 8; ++n) {
#pragma unroll
    for (int m = 1; m < 64; m <<= 1) acc[n] += __shfl_xor(acc[n], m, 64);
  }
  if (lane == 0) {
#pragma unroll
    for (int n = 0; n < 8; ++n)
      fbuf[(size_t)wid * 8 + n] = sigmoidf_fast(acc[n] + bfv[n]);
  }
}

// ---------------- causal depthwise conv (KC=4) + SiLU, all 3 tensors ----------------
__global__ void conv_silu_kernel(const float* __restrict__ pre,
                                 const float* __restrict__ cwq,
                                 const float* __restrict__ cwk,
                                 const float* __restrict__ cwv,
                                 float* __restrict__ outb) {
  int i = blockIdx.x * blockDim.x + threadIdx.x;  // B*L*512
  int which = blockIdx.y;
  const float* cw = (which == 0) ? cwq : (which == 1) ? cwk : cwv;
  const float* p = pre + (size_t)which * 2097152 + i;
  int c = i & 511;
  int l = (i >> 9) & 1023;
  float w0 = cw[c * 4 + 0], w1 = cw[c * 4 + 1], w2 = cw[c * 4 + 2], w3 = cw[c * 4 + 3];
  float acc = w3 * p[0];
  if (l >= 1) acc += w2 * p[-512];
  if (l >= 2) acc += w1 * p[-1024];
  if (l >= 3) acc += w0 * p[-1536];
  outb[(size_t)which * 2097152 + i] = acc * sigmoidf_fast(acc);
}

// ---------------- plain bf16 MFMA GEMM: C(M,Nd) = A * Bt^T ----------------
__global__ __launch_bounds__(256) void gemm_bf16_kernel(
    const unsigned short* __restrict__ A, const unsigned short* __restrict__ Bt,
    float* __restrict__ C, int Kd, int Nd, size_t BtStride, size_t CStride) {
  __shared__ unsigned short Ash[128][40];
  __shared__ unsigned short Bsh[128][40];
  const int tid = threadIdx.x;
  const int wave = tid >> 6, lane = tid & 63;
  const int g = lane >> 4, lr = lane & 15;
  const int m0 = blockIdx.x * 128, n0 = blockIdx.y * 128;
  const unsigned short* Bz = Bt + blockIdx.z * BtStride;
  float* Cz = C + blockIdx.z * CStride;
  const int wm = (wave >> 1) * 64, wn = (wave & 1) * 64;

  f32x4 acc[4][4];
#pragma unroll
  for (int a = 0; a < 4; ++a)
#pragma unroll
    for (int bq = 0; bq < 4; ++bq) acc[a][bq] = (f32x4){0.f, 0.f, 0.f, 0.f};

  for (int k0 = 0; k0 < Kd; k0 += 32) {
#pragma unroll
    for (int it = 0; it < 2; ++it) {
      int cch = tid + 256 * it;
      int r = cch >> 2, cc = cch & 3;
      *(i32x4*)&Ash[r][cc * 8] = *(const i32x4*)(A + (size_t)(m0 + r) * Kd + k0 + cc * 8);
      *(i32x4*)&Bsh[r][cc * 8] = *(const i32x4*)(Bz + (size_t)(n0 + r) * Kd + k0 + cc * 8);
    }
    __syncthreads();
    short8 af[4], bfr[4];
#pragma unroll
    for (int mt = 0; mt < 4; ++mt) af[mt] = *(const short8*)&Ash[wm + mt * 16 + lr][g * 8];
#pragma unroll
    for (int nt = 0; nt < 4; ++nt) bfr[nt] = *(const short8*)&Bsh[wn + nt * 16 + lr][g * 8];
#pragma unroll
    for (int mt = 0; mt < 4; ++mt)
#pragma unroll
      for (int nt = 0; nt < 4; ++nt)
        acc[mt][nt] = __builtin_amdgcn_mfma_f32_16x16x32_bf16(af[mt], bfr[nt], acc[mt][nt], 0, 0, 0);
    __syncthreads();
  }
#pragma unroll
  for (int mt = 0; mt < 4; ++mt)
#pragma unroll
    for (int nt = 0; nt < 4; ++nt)
#pragma unroll
      for (int r = 0; r < 4; ++r) {
        int m = m0 + wm + mt * 16 + g * 4 + r;
        int n = n0 + wn + nt * 16 + lr;
        Cz[(size_t)m * Nd + n] = acc[mt][nt][r];
      }
}

// ---------------- split-bf16 (3-term f32-emulation) GEMM ----------------
__global__ __launch_bounds__(256) void gemm_split_kernel(
    const unsigned short* __restrict__ Ah, const unsigned short* __restrict__ Al,
    const unsigned short* __restrict__ Bth, const unsigned short* __restrict__ Btl,
    float* __restrict__ C, int Kd, int Nd, size_t BtStride, size_t CStride) {
  __shared__ unsigned short AshH[128][40];
  __shared__ unsigned short AshL[128][40];
  __shared__ unsigned short BshH[128][40];
  __shared__ unsigned short BshL[128][40];
  const int tid = threadIdx.x;
  const int wave = tid >> 6, lane = tid & 63;
  const int g = lane >> 4, lr = lane & 15;
  const int m0 = blockIdx.x * 128, n0 = blockIdx.y * 128;
  const unsigned short* Bzh = Bth + blockIdx.z * BtStride;
  const unsigned short* Bzl = Btl + blockIdx.z * BtStride;
  float* Cz = C + blockIdx.z * CStride;
  const int wm = (wave >> 1) * 64, wn = (wave & 1) * 64;

  f32x4 acc[4][4];
#pragma unroll
  for (int a = 0; a < 4; ++a)
#pragma unroll
    for (int bq = 0; bq < 4; ++bq) acc[a][bq] = (f32x4){0.f, 0.f, 0.f, 0.f};

  for (int k0 = 0; k0 < Kd; k0 += 32) {
#pragma unroll
    for (int it = 0; it < 2; ++it) {
      int cch = tid + 256 * it;
      int r = cch >> 2, cc = cch & 3;
      size_t ao = (size_t)(m0 + r) * Kd + k0 + cc * 8;
      size_t bo = (size_t)(n0 + r) * Kd + k0 + cc * 8;
      *(i32x4*)&AshH[r][cc * 8] = *(const i32x4*)(Ah + ao);
      *(i32x4*)&AshL[r][cc * 8] = *(const i32x4*)(Al + ao);
      *(i32x4*)&BshH[r][cc * 8] = *(const i32x4*)(Bzh + bo);
      *(i32x4*)&BshL[r][cc * 8] = *(const i32x4*)(Bzl + bo);
    }
    __syncthreads();
    short8 afh[4], afl[4], bfh[4], bfl[4];
#pragma unroll
    for (int mt = 0; mt < 4; ++mt) {
      afh[mt] = *(const short8*)&AshH[wm + mt * 16 + lr][g * 8];
      afl[mt] = *(const short8*)&AshL[wm + mt * 16 + lr][g * 8];
    }
#pragma unroll
    for (int nt = 0; nt < 4; ++nt) {
      bfh[nt] = *(const short8*)&BshH[wn + nt * 16 + lr][g * 8];
      bfl[nt] = *(const short8*)&BshL[wn + nt * 16 + lr][g * 8];
    }
#pragma unroll
    for (int mt = 0; mt < 4; ++mt)
#pragma unroll
      for (int nt = 0; nt < 4; ++nt) {
        f32x4 a = acc[mt][nt];
        a = __builtin_amdgcn_mfma_f32_16x16x32_bf16(afl[mt], bfh[nt], a, 0, 0, 0);
        a = __builtin_amdgcn_mfma_f32_16x16x32_bf16(afh[mt], bfl[nt], a, 0, 0, 0);
        a = __builtin_amdgcn_mfma_f32_16x16x32_bf16(afh[mt], bfh[nt], a, 0, 0, 0);
        acc[mt][nt] = a;
      }
    __syncthreads();
  }
#pragma unroll
  for (int mt = 0; mt < 4; ++mt)
#pragma unroll
    for (int nt = 0; nt < 4; ++nt)
#pragma unroll
      for (int r = 0; r < 4; ++r) {
        int m = m0 + wm + mt * 16 + g * 4 + r;
        int n = n0 + wn + nt * 16 + lr;
        Cz[(size_t)m * Nd + n] = acc[mt][nt][r];
      }
}

// ---------------- recurrent scan: k-slice split + 2-chain-per-wave ILP ----------------
// r11-verified per-chain structure. r12: each block handles TWO chains (same n,
// b = 2bp and 2bp+1 -> shared W fragments), same k-slice; every wave runs both
// chains' step back-to-back so one chain's latency stalls absorb the other's
// issue (r8 failed because waves served ONE chain in lockstep -> zero ILP).
// 64 blocks x 256 thr. Order per step: reads -> MFMAs -> blend -> pack+write -> y.
// Slice H planes (ping-pong): row lr at byte lr*128, elem v at (2v)^((lr&7)<<4).
__global__ __launch_bounds__(256) void scan_kernel(
    const float* __restrict__ qbuf, const float* __restrict__ kbuf,
    const float* __restrict__ vbuf, const float* __restrict__ fbuf,
    const float* __restrict__ W, unsigned short* __restrict__ ypart,
    float* __restrict__ Hout) {
  const int tid = threadIdx.x;
  const int wave = tid >> 6, lane = tid & 63;
  const int g = lane >> 4, lr = lane & 15;
  const int pi = blockIdx.x >> 2, ks = blockIdx.x & 3;
  const int n = pi & 7, bp = pi >> 3;
  const int swz = (lr & 7) << 4;

  __shared__ unsigned short Hh[2][2][1024];  // [chain][pp] 16x64 bf16 hi (8 KB)
  __shared__ unsigned short Hl[2][2][1024];  // lo planes (8 KB)
  __shared__ float stage[2][2][16][192];     // [chain][buf] (48 KB)
  __shared__ float fs[2][2][16];
  __shared__ float yst[2][16][64];           // (8 KB)

  // zero plane 0, both chains
  for (int i = tid; i < 512; i += 256) {
    ((unsigned*)Hh[0][0])[i] = 0u; ((unsigned*)Hl[0][0])[i] = 0u;
    ((unsigned*)Hh[1][0])[i] = 0u; ((unsigned*)Hl[1][0])[i] = 0u;
  }

  // W^T split hi/lo fragments -- shared by both chains (same n)
  const float* Wn = W + (size_t)n * 4096;
  short8 Af[2], Alw[2];
#pragma unroll
  for (int s = 0; s < 2; ++s) {
    int wcol = wave * 16 + lr;
    short8 ah, al;
#pragma unroll
    for (int j = 0; j < 8; ++j) {
      float wv = Wn[(size_t)(s * 32 + g * 8 + j) * 64 + wcol];
      unsigned short hb = f2bf(wv);
      ah[j] = (short)hb;
      al[j] = (short)f2bf(wv - bf2f(hb));
    }
    Af[s] = ah; Alw[s] = al;
  }

  // chunk staging: per chain 768 f32x4, 256 threads x 3
  auto stage_chunk = [&](int cc, int buf) {
#pragma unroll
    for (int ch = 0; ch < 2; ++ch) {
      const int bb = bp * 2 + ch;
#pragma unroll
      for (int i = 0; i < 3; ++i) {
        int fi = tid + i * 256;
        int st = fi / 48, un = fi - st * 48;
        const float* basep = (un < 16) ? qbuf : (un < 32) ? kbuf : vbuf;
        f32x4 val = *(const f32x4*)(basep + (size_t)(bb * 1024 + cc * 16 + st) * 512 +
                                    n * 64 + (un & 15) * 4);
        *(f32x4*)&stage[ch][buf][st][un * 4] = val;
      }
      if (tid < 16)
        fs[ch][buf][tid] = fbuf[(size_t)(bb * 1024 + cc * 16 + tid) * 8 + n];
    }
  };

  f32x4 H0 = (f32x4){0.f, 0.f, 0.f, 0.f};  // chain0: H[ks*16+lr][w=16*wave+4g+r]
  f32x4 H1 = (f32x4){0.f, 0.f, 0.f, 0.f};  // chain1
  int sb = 0, pp = 0;

  stage_chunk(0, 0);
  __syncthreads();

  const f32x4 zf = (f32x4){0.f, 0.f, 0.f, 0.f};
  const int bo0 = (16 * g) ^ swz;
  const int bo1 = (64 + 16 * g) ^ swz;
  const int wo = (32 * wave + 8 * g) ^ swz;
  const float K2L2E = 2.885390081777927f;   // 2*log2(e)
  const int kg = ks * 16 + lr;

  for (int c = 0; c < 64; ++c) {
    if (c < 63) stage_chunk(c + 1, sb ^ 1);
    for (int tl = 0; tl < 16; ++tl) {
      const float* s0 = &stage[0][sb][tl][0];
      const float* s1 = &stage[1][sb][tl][0];

      // B-frags, both chains (8 x ds_read_b128)
      const char* h0h = (const char*)(Hh[0][pp] + lr * 64);
      const char* h0l = (const char*)(Hl[0][pp] + lr * 64);
      const char* h1h = (const char*)(Hh[1][pp] + lr * 64);
      const char* h1l = (const char*)(Hl[1][pp] + lr * 64);
      short8 Bh0_0 = *(const short8*)(h0h + bo0);
      short8 Bh1_0 = *(const short8*)(h0h + bo1);
      short8 Bl0_0 = *(const short8*)(h0l + bo0);
      short8 Bl1_0 = *(const short8*)(h0l + bo1);
      short8 Bh0_1 = *(const short8*)(h1h + bo0);
      short8 Bh1_1 = *(const short8*)(h1h + bo1);
      short8 Bl0_1 = *(const short8*)(h1l + bo0);
      short8 Bl1_1 = *(const short8*)(h1l + bo1);

      // scalar stage reads early (overlap with MFMAs)
      float kv0 = s0[64 + kg], kv1 = s1[64 + kg];
      f32x4 vv0 = *(const f32x4*)(s0 + 128 + wave * 16 + 4 * g);
      f32x4 vv1 = *(const f32x4*)(s1 + 128 + wave * 16 + 4 * g);
      float fc0 = fs[0][sb][tl], fc1 = fs[1][sb][tl];
      float qs0 = s0[kg], qs1 = s1[kg];

      // 12 MFMAs: 4 independent chains of 3 (2 per chain), interleaved
      f32x4 cX0 = __builtin_amdgcn_mfma_f32_16x16x32_bf16(Alw[0], Bh0_0, zf, 0, 0, 0);
      f32x4 cX1 = __builtin_amdgcn_mfma_f32_16x16x32_bf16(Alw[0], Bh0_1, zf, 0, 0, 0);
      f32x4 cY0 = __builtin_amdgcn_mfma_f32_16x16x32_bf16(Alw[1], Bh1_0, zf, 0, 0, 0);
      f32x4 cY1 = __builtin_amdgcn_mfma_f32_16x16x32_bf16(Alw[1], Bh1_1, zf, 0, 0, 0);
      cX0 = __builtin_amdgcn_mfma_f32_16x16x32_bf16(Af[0], Bl0_0, cX0, 0, 0, 0);
      cX1 = __builtin_amdgcn_mfma_f32_16x16x32_bf16(Af[0], Bl0_1, cX1, 0, 0, 0);
      cY0 = __builtin_amdgcn_mfma_f32_16x16x32_bf16(Af[1], Bl1_0, cY0, 0, 0, 0);
      cY1 = __builtin_amdgcn_mfma_f32_16x16x32_bf16(Af[1], Bl1_1, cY1, 0, 0, 0);
      cX0 = __builtin_amdgcn_mfma_f32_16x16x32_bf16(Af[0], Bh0_0, cX0, 0, 0, 0);
      cX1 = __builtin_amdgcn_mfma_f32_16x16x32_bf16(Af[0], Bh0_1, cX1, 0, 0, 0);
      cY0 = __builtin_amdgcn_mfma_f32_16x16x32_bf16(Af[1], Bh1_0, cY0, 0, 0, 0);
      cY1 = __builtin_amdgcn_mfma_f32_16x16x32_bf16(Af[1], Bh1_1, cY1, 0, 0, 0);

      f32x4 a0 = cX0 + cY0;
      f32x4 a1 = cX1 + cY1;

      // tanh + gate blend, both chains
#pragma unroll
      for (int r = 0; r < 4; ++r) {
        float g0 = fmaf(kv0, vv0[r], a0[r]);
        float c0 = fmaf(-2.f, __builtin_amdgcn_rcpf(1.f + __builtin_amdgcn_exp2f(g0 * K2L2E)), 1.f);
        H0[r] = fmaf(fc0, H0[r] - c0, c0);
        float g1 = fmaf(kv1, vv1[r], a1[r]);
        float c1 = fmaf(-2.f, __builtin_amdgcn_rcpf(1.f + __builtin_amdgcn_exp2f(g1 * K2L2E)), 1.f);
        H1[r] = fmaf(fc1, H1[r] - c1, c1);
      }

      // pack + write H_{t+1} to plane pp^1, both chains
      {
        char* w0h = (char*)(Hh[0][pp ^ 1] + lr * 64);
        char* w0l = (char*)(Hl[0][pp ^ 1] + lr * 64);
        unsigned ph0 = cvt_pk_bf16(H0[0], H0[1]);
        unsigned ph1 = cvt_pk_bf16(H0[2], H0[3]);
        float r0 = H0[0] - __builtin_bit_cast(float, ph0 << 16);
        float r1 = H0[1] - __builtin_bit_cast(float, ph0 & 0xFFFF0000u);
        float r2 = H0[2] - __builtin_bit_cast(float, ph1 << 16);
        float r3 = H0[3] - __builtin_bit_cast(float, ph1 & 0xFFFF0000u);
        *(u32x2*)(w0h + wo) = (u32x2){ph0, ph1};
        *(u32x2*)(w0l + wo) = (u32x2){cvt_pk_bf16(r0, r1), cvt_pk_bf16(r2, r3)};
        char* w1h = (char*)(Hh[1][pp ^ 1] + lr * 64);
        char* w1l = (char*)(Hl[1][pp ^ 1] + lr * 64);
        unsigned qh0 = cvt_pk_bf16(H1[0], H1[1]);
        unsigned qh1 = cvt_pk_bf16(H1[2], H1[3]);
        float s0r = H1[0] - __builtin_bit_cast(float, qh0 << 16);
        float s1r = H1[1] - __builtin_bit_cast(float, qh0 & 0xFFFF0000u);
        float s2r = H1[2] - __builtin_bit_cast(float, qh1 << 16);
        float s3r = H1[3] - __builtin_bit_cast(float, qh1 & 0xFFFF0000u);
        *(u32x2*)(w1h + wo) = (u32x2){qh0, qh1};
        *(u32x2*)(w1l + wo) = (u32x2){cvt_pk_bf16(s0r, s1r), cvt_pk_bf16(s2r, s3r)};
      }

      // y slice-partials (after the writes: VALU covers the ds_write drain)
      {
        float y00 = row_sum16(qs0 * H0[0]);
        float y01 = row_sum16(qs0 * H0[1]);
        float y02 = row_sum16(qs0 * H0[2]);
        float y03 = row_sum16(qs0 * H0[3]);
        float y10 = row_sum16(qs1 * H1[0]);
        float y11 = row_sum16(qs1 * H1[1]);
        float y12 = row_sum16(qs1 * H1[2]);
        float y13 = row_sum16(qs1 * H1[3]);
        if (lr == 15) {
          *(f32x4*)&yst[0][tl][wave * 16 + 4 * g] = (f32x4){y00, y01, y02, y03};
          *(f32x4*)&yst[1][tl][wave * 16 + 4 * g] = (f32x4){y10, y11, y12, y13};
        }
      }

      __syncthreads();
      pp ^= 1;
    }

    // flush y slice-partials for this chunk (bf16), both chains, coalesced
    for (int i = tid; i < 2048; i += 256) {
      int ch = i >> 10, r = i & 1023;
      int tl2 = r >> 6, w = r & 63;
      int bb = bp * 2 + ch;
      ypart[(size_t)ks * 2097152 +
            (size_t)(bb * 1024 + c * 16 + tl2) * 512 + n * 64 + w] = f2bf(yst[ch][tl2][w]);
    }
    __syncthreads();   // protect yst + stage reuse
    sb ^= 1;
  }

  // H_final (f32 master): this slice's rows, both chains
  float* Ho0 = Hout + (size_t)((bp * 2 + 0) * 8 + n) * 4096;
  float* Ho1 = Hout + (size_t)((bp * 2 + 1) * 8 + n) * 4096;
  *(f32x4*)&Ho0[(size_t)kg * 64 + wave * 16 + g * 4] = H0;
  *(f32x4*)&Ho1[(size_t)kg * 64 + wave * 16 + g * 4] = H1;
}

// ---------------- sum 4 y slice-partials -> bf16 y ----------------
__global__ void ysum_kernel(const unsigned short* __restrict__ yp,
                            unsigned short* __restrict__ yb) {
  int i = blockIdx.x * 256 + threadIdx.x;   // x4 elems
  u16x4 s0 = ((const u16x4*)yp)[i];
  u16x4 s1 = ((const u16x4*)(yp + 2097152))[i];
  u16x4 s2 = ((const u16x4*)(yp + 2 * 2097152))[i];
  u16x4 s3 = ((const u16x4*)(yp + 3 * 2097152))[i];
  u16x4 o;
#pragma unroll
  for (int j = 0; j < 4; ++j)
    o[j] = f2bf(bf2f(s0[j]) + bf2f(s1[j]) + bf2f(s2[j]) + bf2f(s3[j]));
  ((u16x4*)yb)[i] = o;
}

// ---------------- launch ----------------
extern "C" void kernel_launch(void* const* d_in, const int* in_sizes, int n_in,
                              void* d_out, int out_size, void* d_ws, size_t ws_size,
                              hipStream_t stream) {
  const float* x   = (const float*)d_in[0];
  const float* Wq  = (const float*)d_in[1];
  const float* Wk  = (const float*)d_in[2];
  const float* Wv  = (const float*)d_in[3];
  const float* Wf  = (const float*)d_in[4];
  const float* bfv = (const float*)d_in[5];
  const float* cwq = (const float*)d_in[6];
  const float* cwk = (const float*)d_in[7];
  const float* cwv = (const float*)d_in[8];
  const float* W   = (const float*)d_in[9];
  const float* Wo  = (const float*)d_in[10];
  float* outp = (float*)d_out;

  char* ws = (char*)d_ws;
  size_t off = 0;
  auto alloc = [&](size_t bytes) {
    char* pp = ws + off;
    off = (off + bytes + 255) & ~(size_t)255;
    return pp;
  };
  unsigned short* xbh  = (unsigned short*)alloc((size_t)4194304 * 2);
  unsigned short* xbl  = (unsigned short*)alloc((size_t)4194304 * 2);
  unsigned short* wtbh = (unsigned short*)alloc((size_t)3 * 524288 * 2);
  unsigned short* wtbl = (unsigned short*)alloc((size_t)3 * 524288 * 2);
  float* pre  = (float*)alloc((size_t)3 * 2097152 * 4);   // aliased: y partials
  float* qkv  = (float*)alloc((size_t)3 * 2097152 * 4);
  float* fbuf = (float*)alloc((size_t)32768 * 4);
  unsigned short* yb  = (unsigned short*)alloc((size_t)2097152 * 2);
  unsigned short* wot = (unsigned short*)alloc((size_t)524288 * 2);
  unsigned short* ypart = (unsigned short*)pre;  // pre is dead after conv_silu

  // casts / transposes (split hi/lo for the amplified paths)
  cast_split_kernel<<<4096, 256, 0, stream>>>(x, xbh, xbl, 1048576);
  tcast_split_kernel<<<2048, 256, 0, stream>>>(Wq, wtbh, wtbl, 1024, 512);
  tcast_split_kernel<<<2048, 256, 0, stream>>>(Wk, wtbh + 524288, wtbl + 524288, 1024, 512);
  tcast_split_kernel<<<2048, 256, 0, stream>>>(Wv, wtbh + 2 * 524288, wtbl + 2 * 524288, 1024, 512);
  // gate
  fgate_kernel<<<1024, 256, 0, stream>>>(x, Wf, bfv, fbuf);
  // q pre-activation: plain bf16 (un-amplified path)
  dim3 gq(32, 4, 1);
  gemm_bf16_kernel<<<gq, 256, 0, stream>>>(xbh, wtbh, pre, 1024, 512,
                                           (size_t)0, (size_t)0);
  // k,v pre-activations: split-bf16 (amplified path)
  dim3 gkv(32, 4, 2);
  gemm_split_kernel<<<gkv, 256, 0, stream>>>(xbh, xbl, wtbh + 524288, wtbl + 524288,
                                             pre + 2097152, 1024, 512,
                                             (size_t)524288, (size_t)2097152);
  // conv + silu (all three in one launch); pre is dead afterwards
  dim3 gc(8192, 3, 1);
  conv_silu_kernel<<<gc, 256, 0, stream>>>(pre, cwq, cwk, cwv, qkv);
  // recurrent scan: 64 blocks (16 chain-pairs x 4 k-slices) x 256 threads
  scan_kernel<<<64, 256, 0, stream>>>(qkv, qkv + 2097152, qkv + 2 * 2097152, fbuf, W,
                                      ypart, outp + 4194304);
  // fold slice partials -> yb (bf16)
  ysum_kernel<<<2048, 256, 0, stream>>>(ypart, yb);
  // output projection
  tcast_kernel<<<2048, 256, 0, stream>>>(Wo, wot, 512, 1024);
  dim3 g2(32, 8, 1);
  gemm_bf16_kernel<<<g2, 256, 0, stream>>>(yb, wot, outp, 512, 1024, (size_t)0, (size_t)0);
}

// Round 13
// 895.792 us; speedup vs baseline: 1.0847x; 1.0847x over previous
//
#include <hip/hip_runtime.h>
#include <hip/hip_bf16.h>

typedef __attribute__((ext_vector_type(4))) float f32x4;
typedef __attribute__((ext_vector_type(8))) short short8;
typedef __attribute__((ext_vector_type(4))) int i32x4;
typedef __attribute__((ext_vector_type(2))) unsigned int u32x2;
typedef __attribute__((ext_vector_type(4))) unsigned short u16x4;

static __device__ __forceinline__ unsigned short f2bf(float f) {
  unsigned u = __builtin_bit_cast(unsigned, f);
  u = u + 0x7FFFu + ((u >> 16) & 1u);   // RNE
  return (unsigned short)(u >> 16);
}
static __device__ __forceinline__ float bf2f(unsigned short b) {
  unsigned u = ((unsigned)b) << 16;
  return __builtin_bit_cast(float, u);
}
static __device__ __forceinline__ float sigmoidf_fast(float x) {
  return __builtin_amdgcn_rcpf(1.f + __expf(-x));
}
// packed bf16 pair: low16 = bf16(a), high16 = bf16(b)
static __device__ __forceinline__ unsigned cvt_pk_bf16(float a, float b) {
  unsigned d;
  asm volatile("v_cvt_pk_bf16_f32 %0, %1, %2" : "=v"(d) : "v"(a), "v"(b));
  return d;
}
// Row-wise (16-lane DPP row) inclusive sum; total lands in lane (lane&15)==15.
static __device__ __forceinline__ float row_sum16(float v) {
  int x;
  x = __builtin_amdgcn_update_dpp(0, __builtin_bit_cast(int, v), 0x111, 0xF, 0xF, true);
  v += __builtin_bit_cast(float, x);   // row_shr:1
  x = __builtin_amdgcn_update_dpp(0, __builtin_bit_cast(int, v), 0x112, 0xF, 0xF, true);
  v += __builtin_bit_cast(float, x);   // row_shr:2
  x = __builtin_amdgcn_update_dpp(0, __builtin_bit_cast(int, v), 0x114, 0xF, 0xF, true);
  v += __builtin_bit_cast(float, x);   // row_shr:4
  x = __builtin_amdgcn_update_dpp(0, __builtin_bit_cast(int, v), 0x118, 0xF, 0xF, true);
  v += __builtin_bit_cast(float, x);   // row_shr:8
  return v;
}

// ---------------- cast f32 -> hi/lo bf16 pair (RNE hi) ----------------
__global__ void cast_split_kernel(const float* __restrict__ in,
                                  unsigned short* __restrict__ oh,
                                  unsigned short* __restrict__ ol, int n4) {
  int i = blockIdx.x * blockDim.x + threadIdx.x;
  if (i >= n4) return;
  f32x4 v = ((const f32x4*)in)[i];
  u16x4 h, l;
#pragma unroll
  for (int j = 0; j < 4; ++j) {
    unsigned short hb = f2bf(v[j]);
    h[j] = hb;
    l[j] = f2bf(v[j] - bf2f(hb));
  }
  ((u16x4*)oh)[i] = h;
  ((u16x4*)ol)[i] = l;
}

// ---------------- transpose + cast: (R,C) f32 -> (C,R) bf16 ----------------
__global__ void tcast_kernel(const float* __restrict__ in,
                             unsigned short* __restrict__ out, int R, int C) {
  int i = blockIdx.x * blockDim.x + threadIdx.x;
  if (i >= R * C) return;
  int r = i / C, c = i % C;
  out[(size_t)c * R + r] = f2bf(in[i]);
}

// ---------------- transpose + split cast: (R,C) f32 -> (C,R) hi/lo bf16 ----------------
__global__ void tcast_split_kernel(const float* __restrict__ in,
                                   unsigned short* __restrict__ oh,
                                   unsigned short* __restrict__ ol, int R, int C) {
  int i = blockIdx.x * blockDim.x + threadIdx.x;
  if (i >= R * C) return;
  int r = i / C, c = i % C;
  float v = in[i];
  unsigned short hb = f2bf(v);
  oh[(size_t)c * R + r] = hb;
  ol[(size_t)c * R + r] = f2bf(v - bf2f(hb));
}

// ---------------- f gate: one wave per token row (pure f32) ----------------
__global__ __launch_bounds__(256) void fgate_kernel(const float* __restrict__ x,
                                                    const float* __restrict__ Wf,
                                                    const float* __restrict__ bfv,
                                                    float* __restrict__ fbuf) {
  int wid = (blockIdx.x * blockDim.x + threadIdx.x) >> 6;  // token row 0..4095
  int lane = threadIdx.x & 63;
  const float* xr = x + (size_t)wid * 1024;
  float acc[8] = {0.f, 0.f, 0.f, 0.f, 0.f, 0.f, 0.f, 0.f};
#pragma unroll 4
  for (int it = 0; it < 16; ++it) {
    int d = it * 64 + lane;
    float xv = xr[d];
    f32x4 w0 = *(const f32x4*)(Wf + (size_t)d * 8);
    f32x4 w1 = *(const f32x4*)(Wf + (size_t)d * 8 + 4);
    acc[0] += xv * w0[0]; acc[1] += xv * w0[1];
    acc[2] += xv * w0[2]; acc[3] += xv * w0[3];
    acc[4] += xv * w1[0]; acc[5] += xv * w1[1];
    acc[6] += xv * w1[2]; acc[7] += xv * w1[3];
  }
#pragma unroll
  for (int n = 0; n < 8; ++n) {
#pragma unroll
    for (int m = 1; m < 64; m <<= 1) acc[n] += __shfl_xor(acc[n], m, 64);
  }
  if (lane == 0) {
#pragma unroll
    for (int n = 0; n < 8; ++n)
      fbuf[(size_t)wid * 8 + n] = sigmoidf_fast(acc[n] + bfv[n]);
  }
}

// ---------------- causal depthwise conv (KC=4) + SiLU, all 3 tensors ----------------
__global__ void conv_silu_kernel(const float* __restrict__ pre,
                                 const float* __restrict__ cwq,
                                 const float* __restrict__ cwk,
                                 const float* __restrict__ cwv,
                                 float* __restrict__ outb) {
  int i = blockIdx.x * blockDim.x + threadIdx.x;  // B*L*512
  int which = blockIdx.y;
  const float* cw = (which == 0) ? cwq : (which == 1) ? cwk : cwv;
  const float* p = pre + (size_t)which * 2097152 + i;
  int c = i & 511;
  int l = (i >> 9) & 1023;
  float w0 = cw[c * 4 + 0], w1 = cw[c * 4 + 1], w2 = cw[c * 4 + 2], w3 = cw[c * 4 + 3];
  float acc = w3 * p[0];
  if (l >= 1) acc += w2 * p[-512];
  if (l >= 2) acc += w1 * p[-1024];
  if (l >= 3) acc += w0 * p[-1536];
  outb[(size_t)which * 2097152 + i] = acc * sigmoidf_fast(acc);
}

// ---------------- plain bf16 MFMA GEMM: C(M,Nd) = A * Bt^T ----------------
__global__ __launch_bounds__(256) void gemm_bf16_kernel(
    const unsigned short* __restrict__ A, const unsigned short* __restrict__ Bt,
    float* __restrict__ C, int Kd, int Nd, size_t BtStride, size_t CStride) {
  __shared__ unsigned short Ash[128][40];
  __shared__ unsigned short Bsh[128][40];
  const int tid = threadIdx.x;
  const int wave = tid >> 6, lane = tid & 63;
  const int g = lane >> 4, lr = lane & 15;
  const int m0 = blockIdx.x * 128, n0 = blockIdx.y * 128;
  const unsigned short* Bz = Bt + blockIdx.z * BtStride;
  float* Cz = C + blockIdx.z * CStride;
  const int wm = (wave >> 1) * 64, wn = (wave & 1) * 64;

  f32x4 acc[4][4];
#pragma unroll
  for (int a = 0; a < 4; ++a)
#pragma unroll
    for (int bq = 0; bq < 4; ++bq) acc[a][bq] = (f32x4){0.f, 0.f, 0.f, 0.f};

  for (int k0 = 0; k0 < Kd; k0 += 32) {
#pragma unroll
    for (int it = 0; it < 2; ++it) {
      int cch = tid + 256 * it;
      int r = cch >> 2, cc = cch & 3;
      *(i32x4*)&Ash[r][cc * 8] = *(const i32x4*)(A + (size_t)(m0 + r) * Kd + k0 + cc * 8);
      *(i32x4*)&Bsh[r][cc * 8] = *(const i32x4*)(Bz + (size_t)(n0 + r) * Kd + k0 + cc * 8);
    }
    __syncthreads();
    short8 af[4], bfr[4];
#pragma unroll
    for (int mt = 0; mt < 4; ++mt) af[mt] = *(const short8*)&Ash[wm + mt * 16 + lr][g * 8];
#pragma unroll
    for (int nt = 0; nt < 4; ++nt) bfr[nt] = *(const short8*)&Bsh[wn + nt * 16 + lr][g * 8];
#pragma unroll
    for (int mt = 0; mt < 4; ++mt)
#pragma unroll
      for (int nt = 0; nt < 4; ++nt)
        acc[mt][nt] = __builtin_amdgcn_mfma_f32_16x16x32_bf16(af[mt], bfr[nt], acc[mt][nt], 0, 0, 0);
    __syncthreads();
  }
#pragma unroll
  for (int mt = 0; mt < 4; ++mt)
#pragma unroll
    for (int nt = 0; nt < 4; ++nt)
#pragma unroll
      for (int r = 0; r < 4; ++r) {
        int m = m0 + wm + mt * 16 + g * 4 + r;
        int n = n0 + wn + nt * 16 + lr;
        Cz[(size_t)m * Nd + n] = acc[mt][nt][r];
      }
}

// ---------------- split-bf16 (3-term f32-emulation) GEMM ----------------
__global__ __launch_bounds__(256) void gemm_split_kernel(
    const unsigned short* __restrict__ Ah, const unsigned short* __restrict__ Al,
    const unsigned short* __restrict__ Bth, const unsigned short* __restrict__ Btl,
    float* __restrict__ C, int Kd, int Nd, size_t BtStride, size_t CStride) {
  __shared__ unsigned short AshH[128][40];
  __shared__ unsigned short AshL[128][40];
  __shared__ unsigned short BshH[128][40];
  __shared__ unsigned short BshL[128][40];
  const int tid = threadIdx.x;
  const int wave = tid >> 6, lane = tid & 63;
  const int g = lane >> 4, lr = lane & 15;
  const int m0 = blockIdx.x * 128, n0 = blockIdx.y * 128;
  const unsigned short* Bzh = Bth + blockIdx.z * BtStride;
  const unsigned short* Bzl = Btl + blockIdx.z * BtStride;
  float* Cz = C + blockIdx.z * CStride;
  const int wm = (wave >> 1) * 64, wn = (wave & 1) * 64;

  f32x4 acc[4][4];
#pragma unroll
  for (int a = 0; a < 4; ++a)
#pragma unroll
    for (int bq = 0; bq < 4; ++bq) acc[a][bq] = (f32x4){0.f, 0.f, 0.f, 0.f};

  for (int k0 = 0; k0 < Kd; k0 += 32) {
#pragma unroll
    for (int it = 0; it < 2; ++it) {
      int cch = tid + 256 * it;
      int r = cch >> 2, cc = cch & 3;
      size_t ao = (size_t)(m0 + r) * Kd + k0 + cc * 8;
      size_t bo = (size_t)(n0 + r) * Kd + k0 + cc * 8;
      *(i32x4*)&AshH[r][cc * 8] = *(const i32x4*)(Ah + ao);
      *(i32x4*)&AshL[r][cc * 8] = *(const i32x4*)(Al + ao);
      *(i32x4*)&BshH[r][cc * 8] = *(const i32x4*)(Bzh + bo);
      *(i32x4*)&BshL[r][cc * 8] = *(const i32x4*)(Bzl + bo);
    }
    __syncthreads();
    short8 afh[4], afl[4], bfh[4], bfl[4];
#pragma unroll
    for (int mt = 0; mt < 4; ++mt) {
      afh[mt] = *(const short8*)&AshH[wm + mt * 16 + lr][g * 8];
      afl[mt] = *(const short8*)&AshL[wm + mt * 16 + lr][g * 8];
    }
#pragma unroll
    for (int nt = 0; nt < 4; ++nt) {
      bfh[nt] = *(const short8*)&BshH[wn + nt * 16 + lr][g * 8];
      bfl[nt] = *(const short8*)&BshL[wn + nt * 16 + lr][g * 8];
    }
#pragma unroll
    for (int mt = 0; mt < 4; ++mt)
#pragma unroll
      for (int nt = 0; nt < 4; ++nt) {
        f32x4 a = acc[mt][nt];
        a = __builtin_amdgcn_mfma_f32_16x16x32_bf16(afl[mt], bfh[nt], a, 0, 0, 0);
        a = __builtin_amdgcn_mfma_f32_16x16x32_bf16(afh[mt], bfl[nt], a, 0, 0, 0);
        a = __builtin_amdgcn_mfma_f32_16x16x32_bf16(afh[mt], bfh[nt], a, 0, 0, 0);
        acc[mt][nt] = a;
      }
    __syncthreads();
  }
#pragma unroll
  for (int mt = 0; mt < 4; ++mt)
#pragma unroll
    for (int nt = 0; nt < 4; ++nt)
#pragma unroll
      for (int r = 0; r < 4; ++r) {
        int m = m0 + wm + mt * 16 + g * 4 + r;
        int n = n0 + wn + nt * 16 + lr;
        Cz[(size_t)m * Nd + n] = acc[mt][nt][r];
      }
}

// ---------------- recurrent scan: k-slice split, 2 waves per slice ----------------
// r11-verified structure (one chain+slice per block, ping-pong planes, 1 barrier
// per step, DPP y-reduce). r13 delta: each slice handled by 2 waves instead of 4;
// wave owns TWO w-tiles wb = wave*2+{0,1} (32 w, 12 MFMAs, 8 H f32/lane).
// Doubles per-wave ILP to overlap the exposed latency; halves barrier scope.
// 128 blocks x 128 thr. Slice H planes: row lr at byte lr*128, elem v at
// (2v) ^ ((lr&7)<<4)   [verified swizzle].
__global__ __launch_bounds__(128) void scan_kernel(
    const float* __restrict__ qbuf, const float* __restrict__ kbuf,
    const float* __restrict__ vbuf, const float* __restrict__ fbuf,
    const float* __restrict__ W, unsigned short* __restrict__ ypart,
    float* __restrict__ Hout) {
  const int tid = threadIdx.x;
  const int wave = tid >> 6, lane = tid & 63;
  const int g = lane >> 4, lr = lane & 15;
  const int bz = blockIdx.x;
  const int chain = bz >> 2, ks = bz & 3;
  const int b = chain >> 3, n = chain & 7;
  const int swz = (lr & 7) << 4;

  __shared__ unsigned short Hh[2][1024];   // 16x64 bf16 hi, ping-pong
  __shared__ unsigned short Hl[2][1024];   // lo planes
  __shared__ float stage[2][16][192];      // 24 KB
  __shared__ float fs[2][16];
  __shared__ float yst[16][64];            // 4 KB

  // zero plane 0 (H_0 = 0): 512 u32 per plane
  for (int i = tid; i < 512; i += 128) {
    ((unsigned*)Hh[0])[i] = 0u;
    ((unsigned*)Hl[0])[i] = 0u;
  }

  // W^T split hi/lo fragments: A[m=w][v-chunk], w = (wave*2+wb)*16 + lr
  const float* Wn = W + (size_t)n * 4096;
  short8 Af[2][2], Alw[2][2];   // [wb][s]
#pragma unroll
  for (int wb = 0; wb < 2; ++wb)
#pragma unroll
    for (int s = 0; s < 2; ++s) {
      int wcol = (wave * 2 + wb) * 16 + lr;
      short8 ah, al;
#pragma unroll
      for (int j = 0; j < 8; ++j) {
        float wv = Wn[(size_t)(s * 32 + g * 8 + j) * 64 + wcol];
        unsigned short hb = f2bf(wv);
        ah[j] = (short)hb;
        al[j] = (short)f2bf(wv - bf2f(hb));
      }
      Af[wb][s] = ah; Alw[wb][s] = al;
    }

  // chunk staging: 16 steps x 192 floats = 768 f32x4 by 128 threads (6 each)
  auto stage_chunk = [&](int c, int buf) {
#pragma unroll
    for (int i = 0; i < 6; ++i) {
      int fi = tid + i * 128;
      int st = fi / 48, un = fi - st * 48;
      const float* basep = (un < 16) ? qbuf : (un < 32) ? kbuf : vbuf;
      f32x4 val = *(const f32x4*)(basep + (size_t)(b * 1024 + c * 16 + st) * 512 +
                                  n * 64 + (un & 15) * 4);
      *(f32x4*)&stage[buf][st][un * 4] = val;
    }
    if (tid < 16) fs[buf][tid] = fbuf[(size_t)(b * 1024 + c * 16 + tid) * 8 + n];
  };

  f32x4 HA = (f32x4){0.f, 0.f, 0.f, 0.f};  // H[ks*16+lr][w=(2*wave+0)*16+4g+r]
  f32x4 HB = (f32x4){0.f, 0.f, 0.f, 0.f};  // H[ks*16+lr][w=(2*wave+1)*16+4g+r]
  int sb = 0, pp = 0;

  stage_chunk(0, 0);
  __syncthreads();

  const f32x4 zf = (f32x4){0.f, 0.f, 0.f, 0.f};
  const int bo0 = (16 * g) ^ swz;               // B-frag chunk 0
  const int bo1 = (64 + 16 * g) ^ swz;          // chunk 1
  const int wo0 = (32 * (wave * 2 + 0) + 8 * g) ^ swz;
  const int wo1 = (32 * (wave * 2 + 1) + 8 * g) ^ swz;
  const float K2L2E = 2.885390081777927f;       // 2*log2(e)
  const int kg = ks * 16 + lr;                  // global k row of this lane

  for (int c = 0; c < 64; ++c) {
    if (c < 63) stage_chunk(c + 1, sb ^ 1);
    for (int tl = 0; tl < 16; ++tl) {
      const float* srow = &stage[sb][tl][0];

      // B-frags of H_t slice from plane pp (shared by both wb tiles)
      const char* hrh = (const char*)(Hh[pp] + lr * 64);
      const char* hrl = (const char*)(Hl[pp] + lr * 64);
      short8 Bh0 = *(const short8*)(hrh + bo0);
      short8 Bh1 = *(const short8*)(hrh + bo1);
      short8 Bl0 = *(const short8*)(hrl + bo0);
      short8 Bl1 = *(const short8*)(hrl + bo1);

      // scalar stage reads early (overlap with MFMAs)
      float kval = srow[64 + kg];
      f32x4 vv0 = *(const f32x4*)(srow + 128 + (wave * 2 + 0) * 16 + 4 * g);
      f32x4 vv1 = *(const f32x4*)(srow + 128 + (wave * 2 + 1) * 16 + 4 * g);
      float fc = fs[sb][tl];
      float qs = srow[kg];

      // 12 MFMAs: 3-term split, 4 independent chains of 3 (2 per wb tile)
      f32x4 cX0 = __builtin_amdgcn_mfma_f32_16x16x32_bf16(Alw[0][0], Bh0, zf, 0, 0, 0);
      f32x4 cX1 = __builtin_amdgcn_mfma_f32_16x16x32_bf16(Alw[1][0], Bh0, zf, 0, 0, 0);
      f32x4 cY0 = __builtin_amdgcn_mfma_f32_16x16x32_bf16(Alw[0][1], Bh1, zf, 0, 0, 0);
      f32x4 cY1 = __builtin_amdgcn_mfma_f32_16x16x32_bf16(Alw[1][1], Bh1, zf, 0, 0, 0);
      cX0 = __builtin_amdgcn_mfma_f32_16x16x32_bf16(Af[0][0], Bl0, cX0, 0, 0, 0);
      cX1 = __builtin_amdgcn_mfma_f32_16x16x32_bf16(Af[1][0], Bl0, cX1, 0, 0, 0);
      cY0 = __builtin_amdgcn_mfma_f32_16x16x32_bf16(Af[0][1], Bl1, cY0, 0, 0, 0);
      cY1 = __builtin_amdgcn_mfma_f32_16x16x32_bf16(Af[1][1], Bl1, cY1, 0, 0, 0);
      cX0 = __builtin_amdgcn_mfma_f32_16x16x32_bf16(Af[0][0], Bh0, cX0, 0, 0, 0);
      cX1 = __builtin_amdgcn_mfma_f32_16x16x32_bf16(Af[1][0], Bh0, cX1, 0, 0, 0);
      cY0 = __builtin_amdgcn_mfma_f32_16x16x32_bf16(Af[0][1], Bh1, cY0, 0, 0, 0);
      cY1 = __builtin_amdgcn_mfma_f32_16x16x32_bf16(Af[1][1], Bh1, cY1, 0, 0, 0);

      f32x4 a0 = cX0 + cY0;
      f32x4 a1 = cX1 + cY1;

      // tanh (exp2-fused) + gate blend -> H_{t+1} (f32, exact), both tiles
#pragma unroll
      for (int r = 0; r < 4; ++r) {
        float g0 = fmaf(kval, vv0[r], a0[r]);
        float c0 = fmaf(-2.f, __builtin_amdgcn_rcpf(1.f + __builtin_amdgcn_exp2f(g0 * K2L2E)), 1.f);
        HA[r] = fmaf(fc, HA[r] - c0, c0);
        float g1 = fmaf(kval, vv1[r], a1[r]);
        float c1 = fmaf(-2.f, __builtin_amdgcn_rcpf(1.f + __builtin_amdgcn_exp2f(g1 * K2L2E)), 1.f);
        HB[r] = fmaf(fc, HB[r] - c1, c1);
      }

      // pack (cvt_pk) and write H_{t+1} to plane pp^1, both tiles
      {
        char* hwh = (char*)(Hh[pp ^ 1] + lr * 64);
        char* hwl = (char*)(Hl[pp ^ 1] + lr * 64);
        unsigned ph0 = cvt_pk_bf16(HA[0], HA[1]);
        unsigned ph1 = cvt_pk_bf16(HA[2], HA[3]);
        float r0 = HA[0] - __builtin_bit_cast(float, ph0 << 16);
        float r1 = HA[1] - __builtin_bit_cast(float, ph0 & 0xFFFF0000u);
        float r2 = HA[2] - __builtin_bit_cast(float, ph1 << 16);
        float r3 = HA[3] - __builtin_bit_cast(float, ph1 & 0xFFFF0000u);
        *(u32x2*)(hwh + wo0) = (u32x2){ph0, ph1};
        *(u32x2*)(hwl + wo0) = (u32x2){cvt_pk_bf16(r0, r1), cvt_pk_bf16(r2, r3)};
        unsigned qh0 = cvt_pk_bf16(HB[0], HB[1]);
        unsigned qh1 = cvt_pk_bf16(HB[2], HB[3]);
        float s0 = HB[0] - __builtin_bit_cast(float, qh0 << 16);
        float s1 = HB[1] - __builtin_bit_cast(float, qh0 & 0xFFFF0000u);
        float s2 = HB[2] - __builtin_bit_cast(float, qh1 << 16);
        float s3 = HB[3] - __builtin_bit_cast(float, qh1 & 0xFFFF0000u);
        *(u32x2*)(hwh + wo1) = (u32x2){qh0, qh1};
        *(u32x2*)(hwl + wo1) = (u32x2){cvt_pk_bf16(s0, s1), cvt_pk_bf16(s2, s3)};
      }

      // y slice-partials after the writes (VALU covers the ds_write drain)
      {
        float y0 = row_sum16(qs * HA[0]);
        float y1 = row_sum16(qs * HA[1]);
        float y2 = row_sum16(qs * HA[2]);
        float y3 = row_sum16(qs * HA[3]);
        float y4 = row_sum16(qs * HB[0]);
        float y5 = row_sum16(qs * HB[1]);
        float y6 = row_sum16(qs * HB[2]);
        float y7 = row_sum16(qs * HB[3]);
        if (lr == 15) {
          *(f32x4*)&yst[tl][(wave * 2 + 0) * 16 + 4 * g] = (f32x4){y0, y1, y2, y3};
          *(f32x4*)&yst[tl][(wave * 2 + 1) * 16 + 4 * g] = (f32x4){y4, y5, y6, y7};
        }
      }

      __syncthreads();   // 2-wave barrier: plane pp^1 + yst visible
      pp ^= 1;
    }

    // flush y slice-partials for this chunk (bf16), coalesced
    for (int i = tid; i < 1024; i += 128) {
      int tl2 = i >> 6, w = i & 63;
      ypart[(size_t)ks * 2097152 +
            (size_t)(b * 1024 + c * 16 + tl2) * 512 + n * 64 + w] = f2bf(yst[tl2][w]);
    }
    __syncthreads();   // protect yst reuse by next chunk
    sb ^= 1;
  }

  // H_final (f32 master): this slice's rows, both tiles
  float* Ho = Hout + (size_t)(b * 8 + n) * 4096;
  *(f32x4*)&Ho[(size_t)kg * 64 + (wave * 2 + 0) * 16 + g * 4] = HA;
  *(f32x4*)&Ho[(size_t)kg * 64 + (wave * 2 + 1) * 16 + g * 4] = HB;
}

// ---------------- sum 4 y slice-partials -> bf16 y ----------------
__global__ void ysum_kernel(const unsigned short* __restrict__ yp,
                            unsigned short* __restrict__ yb) {
  int i = blockIdx.x * 256 + threadIdx.x;   // x4 elems
  u16x4 s0 = ((const u16x4*)yp)[i];
  u16x4 s1 = ((const u16x4*)(yp + 2097152))[i];
  u16x4 s2 = ((const u16x4*)(yp + 2 * 2097152))[i];
  u16x4 s3 = ((const u16x4*)(yp + 3 * 2097152))[i];
  u16x4 o;
#pragma unroll
  for (int j = 0; j < 4; ++j)
    o[j] = f2bf(bf2f(s0[j]) + bf2f(s1[j]) + bf2f(s2[j]) + bf2f(s3[j]));
  ((u16x4*)yb)[i] = o;
}

// ---------------- launch ----------------
extern "C" void kernel_launch(void* const* d_in, const int* in_sizes, int n_in,
                              void* d_out, int out_size, void* d_ws, size_t ws_size,
                              hipStream_t stream) {
  const float* x   = (const float*)d_in[0];
  const float* Wq  = (const float*)d_in[1];
  const float* Wk  = (const float*)d_in[2];
  const float* Wv  = (const float*)d_in[3];
  const float* Wf  = (const float*)d_in[4];
  const float* bfv = (const float*)d_in[5];
  const float* cwq = (const float*)d_in[6];
  const float* cwk = (const float*)d_in[7];
  const float* cwv = (const float*)d_in[8];
  const float* W   = (const float*)d_in[9];
  const float* Wo  = (const float*)d_in[10];
  float* outp = (float*)d_out;

  char* ws = (char*)d_ws;
  size_t off = 0;
  auto alloc = [&](size_t bytes) {
    char* pp = ws + off;
    off = (off + bytes + 255) & ~(size_t)255;
    return pp;
  };
  unsigned short* xbh  = (unsigned short*)alloc((size_t)4194304 * 2);
  unsigned short* xbl  = (unsigned short*)alloc((size_t)4194304 * 2);
  unsigned short* wtbh = (unsigned short*)alloc((size_t)3 * 524288 * 2);
  unsigned short* wtbl = (unsigned short*)alloc((size_t)3 * 524288 * 2);
  float* pre  = (float*)alloc((size_t)3 * 2097152 * 4);   // aliased: y partials
  float* qkv  = (float*)alloc((size_t)3 * 2097152 * 4);
  float* fbuf = (float*)alloc((size_t)32768 * 4);
  unsigned short* yb  = (unsigned short*)alloc((size_t)2097152 * 2);
  unsigned short* wot = (unsigned short*)alloc((size_t)524288 * 2);
  unsigned short* ypart = (unsigned short*)pre;  // pre is dead after conv_silu

  // casts / transposes (split hi/lo for the amplified paths)
  cast_split_kernel<<<4096, 256, 0, stream>>>(x, xbh, xbl, 1048576);
  tcast_split_kernel<<<2048, 256, 0, stream>>>(Wq, wtbh, wtbl, 1024, 512);
  tcast_split_kernel<<<2048, 256, 0, stream>>>(Wk, wtbh + 524288, wtbl + 524288, 1024, 512);
  tcast_split_kernel<<<2048, 256, 0, stream>>>(Wv, wtbh + 2 * 524288, wtbl + 2 * 524288, 1024, 512);
  // gate
  fgate_kernel<<<1024, 256, 0, stream>>>(x, Wf, bfv, fbuf);
  // q pre-activation: plain bf16 (un-amplified path)
  dim3 gq(32, 4, 1);
  gemm_bf16_kernel<<<gq, 256, 0, stream>>>(xbh, wtbh, pre, 1024, 512,
                                           (size_t)0, (size_t)0);
  // k,v pre-activations: split-bf16 (amplified path)
  dim3 gkv(32, 4, 2);
  gemm_split_kernel<<<gkv, 256, 0, stream>>>(xbh, xbl, wtbh + 524288, wtbl + 524288,
                                             pre + 2097152, 1024, 512,
                                             (size_t)524288, (size_t)2097152);
  // conv + silu (all three in one launch); pre is dead afterwards
  dim3 gc(8192, 3, 1);
  conv_silu_kernel<<<gc, 256, 0, stream>>>(pre, cwq, cwk, cwv, qkv);
  // recurrent scan: 128 blocks (32 chains x 4 k-slices) x 128 threads (2 waves)
  scan_kernel<<<128, 128, 0, stream>>>(qkv, qkv + 2097152, qkv + 2 * 2097152, fbuf, W,
                                       ypart, outp + 4194304);
  // fold slice partials -> yb (bf16)
  ysum_kernel<<<2048, 256, 0, stream>>>(ypart, yb);
  // output projection
  tcast_kernel<<<2048, 256, 0, stream>>>(Wo, wot, 512, 1024);
  dim3 g2(32, 8, 1);
  gemm_bf16_kernel<<<g2, 256, 0, stream>>>(yb, wot, outp, 512, 1024, (size_t)0, (size_t)0);
}